// Round 6
// baseline (216.117 us; speedup 1.0000x reference)
//
#include <hip/hip_runtime.h>

#define NTOK 4096
#define DIMC 1024
#define HEADS 12
#define DH 8
#define QSCALE 0.35355339059327373f   /* 8^-0.5 */
#define LOG2E  1.4426950408889634f
#define LN2    0.6931471805599453f

typedef float f4 __attribute__((ext_vector_type(4)));   // native vector for builtins

// ws layout (floats):
//   Q:  [h][n][8]   (pre-scaled by QSCALE), offset 0,      12*4096*8
//   K:  [h][d][n]   SoA,                    offset KOFF,   12*8*4096
#define KOFF (HEADS * NTOK * DH)

// ---------------- Kernel 1: proj = x @ W^T -> q (AoS, scaled), k (SoA) -----
__global__ __launch_bounds__(256) void k1_proj(const float* __restrict__ x,
                                               const float* __restrict__ W,
                                               float* __restrict__ qk) {
    __shared__ float xs[8 * 1028];         // pad 1024->1028 breaks bank aliasing
    const int t = threadIdx.x;
    const int row0 = blockIdx.x * 8;

    const f4* x4 = (const f4*)(x + (size_t)row0 * DIMC);
    #pragma unroll
    for (int i = 0; i < 8; ++i) {
        int f = t + i * 256;
        int r = f >> 8;
        int c4 = f & 255;
        f4 v = x4[f];
        *(f4*)(&xs[r * 1028 + c4 * 4]) = v;
    }
    __syncthreads();

    const int g  = t >> 2;                 // 0..63 -> owns o = 3g..3g+2
    const int rg = t & 3;                  // owns rows rg*2 .. rg*2+1

    float acc[2][3];
    #pragma unroll
    for (int a = 0; a < 2; ++a)
        #pragma unroll
        for (int m = 0; m < 3; ++m) acc[a][m] = 0.f;

    const float* w0 = W + (size_t)(3 * g) * DIMC;
    #pragma unroll 2
    for (int c = 0; c < DIMC; c += 4) {
        f4 w[3];
        #pragma unroll
        for (int m = 0; m < 3; ++m)
            w[m] = *(const f4*)(w0 + (size_t)m * DIMC + c);
        #pragma unroll
        for (int a = 0; a < 2; ++a) {
            f4 xv = *(const f4*)(&xs[(rg * 2 + a) * 1028 + c]);
            #pragma unroll
            for (int m = 0; m < 3; ++m) {
                acc[a][m] = fmaf(xv.x, w[m].x,
                            fmaf(xv.y, w[m].y,
                            fmaf(xv.z, w[m].z,
                            fmaf(xv.w, w[m].w, acc[a][m]))));
            }
        }
    }

    #pragma unroll
    for (int m = 0; m < 3; ++m) {
        int o   = 3 * g + m;
        int qkf = (o >= 96) ? 1 : 0;
        int oo  = o - 96 * qkf;
        int h   = oo >> 3;
        int d   = oo & 7;
        #pragma unroll
        for (int a = 0; a < 2; ++a) {
            int n = row0 + rg * 2 + a;
            float v = acc[a][m];
            if (!qkf) {
                qk[((size_t)h * NTOK + n) * DH + d] = v * QSCALE;      // Q AoS
            } else {
                qk[KOFF + ((size_t)h * DH + d) * NTOK + n] = v;        // K SoA
            }
        }
    }
}

// ---------------- Kernel 2: 4 rows per wave, wave-independent --------------
__device__ __forceinline__ float log_sigmoid(float s) {
    float mn = fminf(s, 0.f);
    float z  = __builtin_amdgcn_exp2f(fabsf(s) * -LOG2E);   // = exp(-|s|)
    return mn - LN2 * __builtin_amdgcn_logf(1.f + z);       // log2 -> *ln2
}

__global__ __launch_bounds__(256) void k2_gates(const float* __restrict__ qk,
                                                float* __restrict__ out) {
    const int bid  = blockIdx.x;
    const int h    = bid >> 8;              // 256 blocks per head (16 rows each)
    const int i0   = (bid & 255) << 4;
    const int t    = threadIdx.x;
    const int lane = t & 63;
    const int wid  = t >> 6;
    const int r0   = i0 + 4 * wid;          // this wave owns rows r0..r0+3

    // q rows (wave-uniform addresses -> scalar loads)
    float qr[4][8];
    #pragma unroll
    for (int r = 0; r < 4; ++r) {
        const float* qp = qk + ((size_t)h * NTOK + r0 + r) * DH;
        #pragma unroll
        for (int d = 0; d < 8; ++d) qr[r][d] = qp[d];
    }

    const float* ks = qk + KOFF + (size_t)h * DH * NTOK;
    float* ob = out + ((size_t)h * NTOK + r0) * NTOK;

    const int ccmax = (r0 + 3) >> 8;        // last chunk with any j < r0+3

    // ---- upper-triangle chunks: pure zero stores ---------------------------
    f4 z = (f4)(0.f);
    for (int cc = 15; cc > ccmax; --cc) {
        const int j0 = cc * 256 + 4 * lane;
        #pragma unroll
        for (int r = 0; r < 4; ++r)
            __builtin_nontemporal_store(z, (f4*)(ob + (size_t)r * NTOK + j0));
    }

    // ---- computed chunks, descending, per-row carry; all intra-wave --------
    float carry[4];
    #pragma unroll
    for (int r = 0; r < 4; ++r) carry[r] = 0.f;

    for (int cc = ccmax; cc >= 0; --cc) {
        const int j0 = cc * 256 + 4 * lane;

        f4 kv[8];
        #pragma unroll
        for (int d = 0; d < 8; ++d)
            kv[d] = *(const f4*)(ks + (size_t)d * NTOK + j0);

        float g[4][4], tot[4], s[4];
        #pragma unroll
        for (int r = 0; r < 4; ++r) {
            float a0 = 0.f, a1 = 0.f, a2 = 0.f, a3 = 0.f;
            #pragma unroll
            for (int d = 0; d < 8; ++d) {
                const float qd = qr[r][d];
                a0 = fmaf(qd, kv[d].x, a0);
                a1 = fmaf(qd, kv[d].y, a1);
                a2 = fmaf(qd, kv[d].z, a2);
                a3 = fmaf(qd, kv[d].w, a3);
            }
            const int ir = r0 + r;
            float g0 = (j0 + 0 < ir) ? log_sigmoid(a0) : 0.f;
            float g1 = (j0 + 1 < ir) ? log_sigmoid(a1) : 0.f;
            float g2 = (j0 + 2 < ir) ? log_sigmoid(a2) : 0.f;
            float g3 = (j0 + 3 < ir) ? log_sigmoid(a3) : 0.f;
            g2 += g3; g1 += g2; g0 += g1;            // reverse-inclusive suffix
            g[r][0] = g0; g[r][1] = g1; g[r][2] = g2; g[r][3] = g3;
            tot[r] = g0; s[r] = g0;
        }

        // wave-wide inclusive suffix scan, rounds outer / 4 rows inner (ILP)
        #pragma unroll
        for (int off = 1; off < 64; off <<= 1) {
            float v0 = __shfl_down(s[0], off, 64);
            float v1 = __shfl_down(s[1], off, 64);
            float v2 = __shfl_down(s[2], off, 64);
            float v3 = __shfl_down(s[3], off, 64);
            if (lane + off < 64) { s[0] += v0; s[1] += v1; s[2] += v2; s[3] += v3; }
        }

        #pragma unroll
        for (int r = 0; r < 4; ++r) {
            const float base = (s[r] - tot[r]) + carry[r];
            carry[r] += __builtin_amdgcn_readfirstlane(s[r]);   // chunk total (lane 0)
            f4 v;
            v.x = g[r][0] + base;
            v.y = g[r][1] + base;
            v.z = g[r][2] + base;
            v.w = g[r][3] + base;
            __builtin_nontemporal_store(v, (f4*)(ob + (size_t)r * NTOK + j0));
        }
    }
}

extern "C" void kernel_launch(void* const* d_in, const int* in_sizes, int n_in,
                              void* d_out, int out_size, void* d_ws, size_t ws_size,
                              hipStream_t stream) {
    const float* x = (const float*)d_in[0];
    const float* W = (const float*)d_in[1];
    float* out = (float*)d_out;
    float* qk  = (float*)d_ws;               // 3 MB scratch

    hipLaunchKernelGGL(k1_proj, dim3(NTOK / 8), dim3(256), 0, stream, x, W, qk);
    hipLaunchKernelGGL(k2_gates, dim3(HEADS * NTOK / 16), dim3(256), 0, stream, qk, out);
}

// Round 7
// 203.394 us; speedup vs baseline: 1.0626x; 1.0626x over previous
//
#include <hip/hip_runtime.h>

#define NTOK 4096
#define DIMC 1024
#define HEADS 12
#define DH 8
#define QSCALE 0.35355339059327373f   /* 8^-0.5 */
#define LOG2E  1.4426950408889634f
#define LN2    0.6931471805599453f
#define QPRE   (QSCALE * LOG2E)       /* fold log2e into q prescale */

typedef float f4 __attribute__((ext_vector_type(4)));
typedef float f2 __attribute__((ext_vector_type(2)));

// ws layout (floats):
//   Q:  [h][n][8]        (pre-scaled by QPRE), offset 0,    12*4096*8
//   K:  [h][16][8][256]  chunk-tiled SoA,      offset KOFF, 12*8*4096
#define KOFF (HEADS * NTOK * DH)

// ---------------- Kernel 1: proj = x @ W^T -> q (AoS, scaled), k (tiled) ---
__global__ __launch_bounds__(256) void k1_proj(const float* __restrict__ x,
                                               const float* __restrict__ W,
                                               float* __restrict__ qk) {
    __shared__ float xs[8 * 1028];         // pad 1024->1028 breaks bank aliasing
    const int t = threadIdx.x;
    const int row0 = blockIdx.x * 8;

    const f4* x4 = (const f4*)(x + (size_t)row0 * DIMC);
    #pragma unroll
    for (int i = 0; i < 8; ++i) {
        int f = t + i * 256;
        int r = f >> 8;
        int c4 = f & 255;
        f4 v = x4[f];
        *(f4*)(&xs[r * 1028 + c4 * 4]) = v;
    }
    __syncthreads();

    const int g  = t >> 2;                 // 0..63 -> owns o = 3g..3g+2
    const int rg = t & 3;                  // owns rows rg*2 .. rg*2+1

    f2 acc[2][3];
    #pragma unroll
    for (int a = 0; a < 2; ++a)
        #pragma unroll
        for (int m = 0; m < 3; ++m) acc[a][m] = (f2)(0.f);

    const float* w0 = W + (size_t)(3 * g) * DIMC;
    #pragma unroll 2
    for (int c = 0; c < DIMC; c += 4) {
        f4 w[3];
        #pragma unroll
        for (int m = 0; m < 3; ++m)
            w[m] = *(const f4*)(w0 + (size_t)m * DIMC + c);
        #pragma unroll
        for (int a = 0; a < 2; ++a) {
            f4 xv = *(const f4*)(&xs[(rg * 2 + a) * 1028 + c]);
            #pragma unroll
            for (int m = 0; m < 3; ++m) {
                acc[a][m] = __builtin_elementwise_fma(xv.xy, w[m].xy, acc[a][m]);
                acc[a][m] = __builtin_elementwise_fma(xv.zw, w[m].zw, acc[a][m]);
            }
        }
    }

    #pragma unroll
    for (int m = 0; m < 3; ++m) {
        int o   = 3 * g + m;
        int qkf = (o >= 96) ? 1 : 0;
        int oo  = o - 96 * qkf;
        int h   = oo >> 3;
        int d   = oo & 7;
        #pragma unroll
        for (int a = 0; a < 2; ++a) {
            int n = row0 + rg * 2 + a;
            float v = acc[a][m].x + acc[a][m].y;
            if (!qkf) {
                qk[((size_t)h * NTOK + n) * DH + d] = v * QPRE;        // Q AoS
            } else {
                qk[KOFF + (((size_t)h * 16 + (n >> 8)) * DH + d) * 256 + (n & 255)] = v;
            }
        }
    }
}

// ---------------- Kernel 2: 2 rows per wave, log2-domain, pk math ----------
__device__ __forceinline__ float lsig2(float u) {
    // logsigmoid in log2 units: min(u,0) - log2(1 + 2^-|u|)   (u = s*log2e)
    float mn = fminf(u, 0.f);
    float z  = __builtin_amdgcn_exp2f(-fabsf(u));   // -|u| is a free modifier
    return mn - __builtin_amdgcn_logf(1.f + z);     // v_log_f32 = log2
}

__global__ __launch_bounds__(256) void k2_gates(const float* __restrict__ qk,
                                                float* __restrict__ out) {
    const int bid  = blockIdx.x;
    const int h    = bid >> 9;              // 512 blocks per head
    const int i0   = (bid & 511) << 3;      // 8 rows per block
    const int t    = threadIdx.x;
    const int lane = t & 63;
    const int wid  = t >> 6;
    const int r0   = i0 + 2 * wid;          // this wave owns rows r0, r0+1
    const int r1   = r0 + 1;

    const float* qrow = qk + ((size_t)h * NTOK + r0) * DH;
    f2 q0s[8], q1s[8];
    #pragma unroll
    for (int d = 0; d < 8; ++d) {
        q0s[d] = (f2)(qrow[d]);
        q1s[d] = (f2)(qrow[DH + d]);
    }

    const float* kh = qk + KOFF + (size_t)h * (16 * DH * 256) + 4 * lane;
    float* o0 = out + ((size_t)h * NTOK + r0) * NTOK;
    float* o1 = o0 + NTOK;

    const int cb = r0 >> 8;                 // boundary chunk (holds j ~ r0)

    // ---- upper-triangle chunks: pure zero stores ---------------------------
    f4 z = (f4)(0.f);
    for (int cc = 15; cc > cb; --cc) {
        const int j0 = cc * 256 + 4 * lane;
        __builtin_nontemporal_store(z, (f4*)(o0 + j0));
        __builtin_nontemporal_store(z, (f4*)(o1 + j0));
    }

    float carry0, carry1;

    // ---- boundary chunk cc = cb: masked compute ----------------------------
    {
        const int j0 = cb * 256 + 4 * lane;
        const float* kc = kh + (size_t)cb * (DH * 256);

        f4 kv[8];
        #pragma unroll
        for (int d = 0; d < 8; ++d) kv[d] = *(const f4*)(kc + d * 256);

        f2 A0 = (f2)(0.f), B0 = (f2)(0.f), A1 = (f2)(0.f), B1 = (f2)(0.f);
        #pragma unroll
        for (int d = 0; d < 8; ++d) {
            A0 = __builtin_elementwise_fma(kv[d].xy, q0s[d], A0);
            B0 = __builtin_elementwise_fma(kv[d].zw, q0s[d], B0);
            A1 = __builtin_elementwise_fma(kv[d].xy, q1s[d], A1);
            B1 = __builtin_elementwise_fma(kv[d].zw, q1s[d], B1);
        }

        float g0[4], g1[4];
        g0[0] = (j0 + 0 < r0) ? lsig2(A0.x) : 0.f;
        g0[1] = (j0 + 1 < r0) ? lsig2(A0.y) : 0.f;
        g0[2] = (j0 + 2 < r0) ? lsig2(B0.x) : 0.f;
        g0[3] = (j0 + 3 < r0) ? lsig2(B0.y) : 0.f;
        g1[0] = (j0 + 0 < r1) ? lsig2(A1.x) : 0.f;
        g1[1] = (j0 + 1 < r1) ? lsig2(A1.y) : 0.f;
        g1[2] = (j0 + 2 < r1) ? lsig2(B1.x) : 0.f;
        g1[3] = (j0 + 3 < r1) ? lsig2(B1.y) : 0.f;

        g0[2] += g0[3]; g0[1] += g0[2]; g0[0] += g0[1];
        g1[2] += g1[3]; g1[1] += g1[2]; g1[0] += g1[1];
        const float t0 = g0[0], t1 = g1[0];
        float s0 = t0, s1 = t1;
        #pragma unroll
        for (int off = 1; off < 64; off <<= 1) {
            float v0 = __shfl_down(s0, off, 64);
            float v1 = __shfl_down(s1, off, 64);
            if (lane + off < 64) { s0 += v0; s1 += v1; }
        }
        const float base0 = s0 - t0;
        const float base1 = s1 - t1;
        carry0 = __builtin_amdgcn_readfirstlane(s0);
        carry1 = __builtin_amdgcn_readfirstlane(s1);

        f4 gv0 = {g0[0], g0[1], g0[2], g0[3]};
        f4 gv1 = {g1[0], g1[1], g1[2], g1[3]};
        f4 ov0 = (gv0 + base0) * LN2;
        f4 ov1 = (gv1 + base1) * LN2;
        __builtin_nontemporal_store(ov0, (f4*)(o0 + j0));
        __builtin_nontemporal_store(ov1, (f4*)(o1 + j0));
    }

    // ---- interior chunks: unmasked, descending with carry ------------------
    for (int cc = cb - 1; cc >= 0; --cc) {
        const int j0 = cc * 256 + 4 * lane;
        const float* kc = kh + (size_t)cc * (DH * 256);

        f4 kv[8];
        #pragma unroll
        for (int d = 0; d < 8; ++d) kv[d] = *(const f4*)(kc + d * 256);

        f2 A0 = (f2)(0.f), B0 = (f2)(0.f), A1 = (f2)(0.f), B1 = (f2)(0.f);
        #pragma unroll
        for (int d = 0; d < 8; ++d) {
            A0 = __builtin_elementwise_fma(kv[d].xy, q0s[d], A0);
            B0 = __builtin_elementwise_fma(kv[d].zw, q0s[d], B0);
            A1 = __builtin_elementwise_fma(kv[d].xy, q1s[d], A1);
            B1 = __builtin_elementwise_fma(kv[d].zw, q1s[d], B1);
        }

        float g0[4], g1[4];
        g0[0] = lsig2(A0.x); g0[1] = lsig2(A0.y);
        g0[2] = lsig2(B0.x); g0[3] = lsig2(B0.y);
        g1[0] = lsig2(A1.x); g1[1] = lsig2(A1.y);
        g1[2] = lsig2(B1.x); g1[3] = lsig2(B1.y);

        g0[2] += g0[3]; g0[1] += g0[2]; g0[0] += g0[1];
        g1[2] += g1[3]; g1[1] += g1[2]; g1[0] += g1[1];
        const float t0 = g0[0], t1 = g1[0];
        float s0 = t0, s1 = t1;
        #pragma unroll
        for (int off = 1; off < 64; off <<= 1) {
            float v0 = __shfl_down(s0, off, 64);
            float v1 = __shfl_down(s1, off, 64);
            if (lane + off < 64) { s0 += v0; s1 += v1; }
        }
        const float base0 = (s0 - t0) + carry0;
        const float base1 = (s1 - t1) + carry1;
        carry0 += __builtin_amdgcn_readfirstlane(s0);
        carry1 += __builtin_amdgcn_readfirstlane(s1);

        f4 gv0 = {g0[0], g0[1], g0[2], g0[3]};
        f4 gv1 = {g1[0], g1[1], g1[2], g1[3]};
        f4 ov0 = (gv0 + base0) * LN2;
        f4 ov1 = (gv1 + base1) * LN2;
        __builtin_nontemporal_store(ov0, (f4*)(o0 + j0));
        __builtin_nontemporal_store(ov1, (f4*)(o1 + j0));
    }
}

extern "C" void kernel_launch(void* const* d_in, const int* in_sizes, int n_in,
                              void* d_out, int out_size, void* d_ws, size_t ws_size,
                              hipStream_t stream) {
    const float* x = (const float*)d_in[0];
    const float* W = (const float*)d_in[1];
    float* out = (float*)d_out;
    float* qk  = (float*)d_ws;               // 3 MB scratch

    hipLaunchKernelGGL(k1_proj, dim3(NTOK / 8), dim3(256), 0, stream, x, W, qk);
    hipLaunchKernelGGL(k2_gates, dim3(HEADS * NTOK / 8), dim3(256), 0, stream, qk, out);
}